// Round 15
// baseline (2268.278 us; speedup 1.0000x reference)
//
#include <hip/hip_runtime.h>

#define NB 8
#define KNBR 8
#define SCAP 256
#define PSTR 4096   // partials row stride (max producer grid)

// ---------------- pack: ref4[r] = (x,y,z,|p|^2) ----------------
__global__ void pack_kernel(const float* __restrict__ xyz, float4* __restrict__ outp, int N) {
  int r = blockIdx.x * 256 + threadIdx.x;
  int b = r / N, n = r - b * N;
  const float* xb = xyz + (size_t)b * 3 * N;
  float x = xb[n], y = xb[N + n], z = xb[2 * N + n];
  outp[r] = make_float4(x, y, z, x * x + y * y + z * z);
}

// ---------------- KNN: wave-per-query, global packed refs, tau-filter + compact (exact) ----------
template<bool EXCL>
__global__ __launch_bounds__(256) void knn_kernel(const float4* __restrict__ ref4,
                                                  const float* __restrict__ qry,
                                                  int Nr, int Nq, int* __restrict__ idx_out) {
  __shared__ float2 surv[4][SCAP];      // 8 KB
  int b = blockIdx.y;
  int wid = threadIdx.x >> 6, lane = threadIdx.x & 63;
  int qi = blockIdx.x * 4 + wid;
  const float4* rb = ref4 + (size_t)b * Nr;
  const float* qb = qry + (size_t)b * 3 * Nq;
  float m2qx = -2.f * qb[qi], m2qy = -2.f * qb[Nq + qi], m2qz = -2.f * qb[2 * Nq + qi];
  float bd[8]; int bi[8];
#pragma unroll
  for (int t = 0; t < 8; t++) { bd[t] = 3.4e38f; bi[t] = 0; }
  float4 rr[8];
  // ---- phase 1: exact top-8 of first 512 ----
#pragma unroll
  for (int u = 0; u < 8; u++) rr[u] = rb[u * 64 + lane];
#pragma unroll
  for (int u = 0; u < 8; u++) {
    float d = fmaf(m2qx, rr[u].x, fmaf(m2qy, rr[u].y, fmaf(m2qz, rr[u].z, rr[u].w)));
    int j = u * 64 + lane;
    if (EXCL) d = (j == qi) ? 3.4e38f : d;
    if (d < bd[7]) {
      bd[7] = d; bi[7] = j;
#pragma unroll
      for (int t = 7; t > 0; t--)
        if (bd[t] < bd[t - 1]) {
          float td = bd[t]; bd[t] = bd[t - 1]; bd[t - 1] = td;
          int ti = bi[t]; bi[t] = bi[t - 1]; bi[t - 1] = ti;
        }
    }
  }
  {  // merge across lanes; replicate merged top-8 into every lane
    float nd[8]; int ni[8];
#pragma unroll
    for (int r = 0; r < 8; r++) {
      float d = bd[0]; int ix = bi[0];
#pragma unroll
      for (int off = 32; off; off >>= 1) {
        float d2 = __shfl_xor(d, off); int i2 = __shfl_xor(ix, off);
        if (d2 < d || (d2 == d && i2 < ix)) { d = d2; ix = i2; }
      }
      if (bd[0] == d && bi[0] == ix) {
#pragma unroll
        for (int t = 0; t < 7; t++) { bd[t] = bd[t + 1]; bi[t] = bi[t + 1]; }
        bd[7] = 3.4e38f;
      }
      nd[r] = d; ni[r] = ix;
    }
#pragma unroll
    for (int t = 0; t < 8; t++) { bd[t] = nd[t]; bi[t] = ni[t]; }
  }
  float tau = bd[7];
  // ---- phase 2: filter + ballot-compact ----
  int scnt = 0;
  for (int base = 512; base < Nr; base += 512) {
#pragma unroll
    for (int u = 0; u < 8; u++) rr[u] = rb[base + u * 64 + lane];
#pragma unroll
    for (int u = 0; u < 8; u++) {
      float d = fmaf(m2qx, rr[u].x, fmaf(m2qy, rr[u].y, fmaf(m2qz, rr[u].z, rr[u].w)));
      int gj = base + u * 64 + lane;
      bool pass = d < tau;
      if (EXCL) pass = pass && (gj != qi);
      if (__any(pass)) {
        unsigned long long mask = __ballot(pass);
        int below = (int)__builtin_amdgcn_mbcnt_hi(
            (unsigned)(mask >> 32), __builtin_amdgcn_mbcnt_lo((unsigned)mask, 0u));
        if (pass) {
          int pos = scnt + below;
          if (pos < SCAP) surv[wid][pos] = make_float2(d, __int_as_float(gj));
        }
        scnt += (int)__popcll(mask);
      }
    }
  }
  // ---- phase 3: insert survivors, final exact wave merge ----
  int nsurv = min(scnt, SCAP);
  for (int s2 = lane; s2 < nsurv; s2 += 64) {
    float2 v = surv[wid][s2];
    float d = v.x; int gj = __float_as_int(v.y);
    if (d < bd[7]) {
      bd[7] = d; bi[7] = gj;
#pragma unroll
      for (int t = 7; t > 0; t--)
        if (bd[t] < bd[t - 1]) {
          float td = bd[t]; bd[t] = bd[t - 1]; bd[t - 1] = td;
          int ti = bi[t]; bi[t] = bi[t - 1]; bi[t - 1] = ti;
        }
    }
  }
  int myout = 0;
#pragma unroll
  for (int r = 0; r < 8; r++) {
    float d = bd[0]; int ix = bi[0];
#pragma unroll
    for (int off = 32; off; off >>= 1) {
      float d2 = __shfl_xor(d, off); int i2 = __shfl_xor(ix, off);
      if (d2 < d || (d2 == d && i2 < ix)) { d = d2; ix = i2; }
    }
    if (bd[0] == d && bi[0] == ix) {
#pragma unroll
      for (int t = 0; t < 7; t++) { bd[t] = bd[t + 1]; bi[t] = bi[t + 1]; }
      bd[7] = 3.4e38f;
    }
    if (lane == r) myout = ix;
  }
  if (lane < 8) idx_out[((size_t)b * Nq + qi) * 8 + lane] = myout;
}

// ---------------- conv0 + fused stats (256 blocks) ----------------
__global__ __launch_bounds__(256) void conv0stats_kernel(const float* __restrict__ xyz,
                                                         const int* __restrict__ idx,
                                                         const float* __restrict__ W0,
                                                         const float* __restrict__ b0,
                                                         float* __restrict__ outp, int N, int rpb,
                                                         float2* __restrict__ partOut) {
  int wid = threadIdx.x >> 6, lane = threadIdx.x & 63;
  int o = 2 * lane;
  float w00 = W0[o * 3], w01 = W0[o * 3 + 1], w02 = W0[o * 3 + 2], bb0 = b0[o];
  float w10 = W0[o * 3 + 3], w11 = W0[o * 3 + 4], w12 = W0[o * 3 + 5], bb1 = b0[o + 1];
  float ps0 = 0, pq0 = 0, ps1 = 0, pq1 = 0;
  for (int p = 0; p < rpb / 4; p++) {
    int r = blockIdx.x * rpb + p * 4 + wid;
    int k = r & 7, pn = r >> 3;
    int n = pn & (N - 1), b = pn / N;
    const float* xb = xyz + (size_t)b * 3 * N;
    int j = idx[(size_t)pn * 8 + k];
    float dx = xb[j] - xb[n], dy = xb[N + j] - xb[N + n], dz = xb[2 * N + j] - xb[2 * N + n];
    float v0 = fmaf(w00, dx, fmaf(w01, dy, fmaf(w02, dz, bb0)));
    float v1 = fmaf(w10, dx, fmaf(w11, dy, fmaf(w12, dz, bb1)));
    *(float2*)&outp[(size_t)r * 128 + o] = make_float2(v0, v1);
    ps0 += v0; pq0 += v0 * v0; ps1 += v1; pq1 += v1 * v1;
  }
  __shared__ float4 red[4][64];
  red[wid][lane] = make_float4(ps0, pq0, ps1, pq1);
  __syncthreads();
  if (threadIdx.x < 64) {
    int t = threadIdx.x;
    float4 a = red[0][t], b2 = red[1][t], c2 = red[2][t], d2 = red[3][t];
    partOut[(size_t)(2 * t) * PSTR + blockIdx.x] =
        make_float2(a.x + b2.x + c2.x + d2.x, a.y + b2.y + c2.y + d2.y);
    partOut[(size_t)(2 * t + 1) * PSTR + blockIdx.x] =
        make_float2(a.z + b2.z + c2.z + d2.z, a.w + b2.w + c2.w + d2.w);
  }
}

// ---------------- finalize (featurenet big grids only) ----------------
__global__ void finalize_kernel(const float2* __restrict__ partials, int nblk, float cntInv,
                                const float* __restrict__ gamma, const float* __restrict__ beta,
                                float2* __restrict__ ss) {
  int c = blockIdx.x;
  const float2* p = partials + (size_t)c * PSTR;
  float s = 0, q = 0;
  for (int i = threadIdx.x; i < nblk; i += 64) { float2 v = p[i]; s += v.x; q += v.y; }
#pragma unroll
  for (int off = 32; off; off >>= 1) { s += __shfl_xor(s, off); q += __shfl_xor(q, off); }
  if (threadIdx.x == 0) {
    float mean = s * cntInv;
    float var = q * cntInv - mean * mean;
    float sc = gamma[c] * rsqrtf(var + 1e-5f);
    ss[c] = make_float2(sc, beta[c] - mean * sc);
  }
}

// ---------------- gemmv: wave-uniform W (scalar loads), lane=row, full-K LDS X ----------------
// Optional COALESCED BN-reduce prologue (partIn != null): wave wv reduces channels
// wv*16..+15; for each channel its 64 lanes stride partials[c][lane + k*64] (coalesced,
// same summation order as finalize_kernel -> bitwise-identical ss). No fences needed:
// producer kernel completed at dispatch boundary.
template<bool GATHER>
__global__ __launch_bounds__(512) void gemmv_kernel(
    const float* __restrict__ Xin, const float2* __restrict__ ssG,
    const float2* __restrict__ partIn, int nblkIn, float cntInvBN,
    const float* __restrict__ gammaN, const float* __restrict__ betaN,
    const int* __restrict__ idx, const float* __restrict__ W,
    const float* __restrict__ bias, float* __restrict__ Y,
    float2* __restrict__ partOut, float* __restrict__ pOut, float* __restrict__ aggOut,
    int N, float alpha, int addShortcut) {
  __shared__ float Xl[128 * 69];   // 34.5 KB
  __shared__ float2 ssL[128];
  int tid = threadIdx.x;
  int l = tid & 63;
  int wv = __builtin_amdgcn_readfirstlane(tid >> 6);
  if (partIn) {
#pragma unroll 1
    for (int j = 0; j < 16; ++j) {
      int c = wv * 16 + j;
      const float2* p = partIn + (size_t)c * PSTR;
      float s = 0.f, q = 0.f;
      for (int i = l; i < nblkIn; i += 64) { float2 v = p[i]; s += v.x; q += v.y; }
#pragma unroll
      for (int off = 32; off; off >>= 1) { s += __shfl_xor(s, off); q += __shfl_xor(q, off); }
      if (l == 0) {
        float mean = s * cntInvBN;
        float var = q * cntInvBN - mean * mean;
        float sc = gammaN[c] * rsqrtf(var + 1e-5f);
        ssL[c] = make_float2(sc, betaN[c] - mean * sc);
      }
    }
  } else {
    if (tid < 128) ssL[tid] = ssG[tid];
  }
  __syncthreads();
  int row0;
  if (GATHER) row0 = (blockIdx.x & 7) * N + (blockIdx.x >> 3) * 64;  // XCD-batch swizzle
  else        row0 = blockIdx.x * 64;
  // ---- stage: wave wv stages rows wv*8..wv*8+7; lane covers channels 2l, 2l+1 ----
  {
    float4 sv = *(const float4*)&ssL[2 * l];   // (scale0,shift0,scale1,shift1)
    for (int r8 = 0; r8 < 8; ++r8) {
      int row = wv * 8 + r8;
      size_t rg = (size_t)(row0 + row);
      float2 v = *(const float2*)&Xin[rg * 128 + 2 * l];
      float s0 = fmaxf(v.x * sv.x + sv.y, 0.f);
      float s1 = fmaxf(v.y * sv.z + sv.w, 0.f);
      if (GATHER) {
        if (pOut) *(float2*)&pOut[rg * 128 + 2 * l] = make_float2(s0, s1);
        int bN = (int)rg & ~(N - 1);
        const int* ir = idx + rg * 8;
        int4 j0 = *(const int4*)ir;
        int4 j1 = *(const int4*)(ir + 4);
        float2 g0 = *(const float2*)&Xin[(size_t)(bN + j0.x) * 128 + 2 * l];
        float2 g1 = *(const float2*)&Xin[(size_t)(bN + j0.y) * 128 + 2 * l];
        float2 g2 = *(const float2*)&Xin[(size_t)(bN + j0.z) * 128 + 2 * l];
        float2 g3 = *(const float2*)&Xin[(size_t)(bN + j0.w) * 128 + 2 * l];
        float2 g4 = *(const float2*)&Xin[(size_t)(bN + j1.x) * 128 + 2 * l];
        float2 g5 = *(const float2*)&Xin[(size_t)(bN + j1.y) * 128 + 2 * l];
        float2 g6 = *(const float2*)&Xin[(size_t)(bN + j1.z) * 128 + 2 * l];
        float2 g7 = *(const float2*)&Xin[(size_t)(bN + j1.w) * 128 + 2 * l];
        s0 += fmaxf(g0.x * sv.x + sv.y, 0.f) + fmaxf(g1.x * sv.x + sv.y, 0.f) +
              fmaxf(g2.x * sv.x + sv.y, 0.f) + fmaxf(g3.x * sv.x + sv.y, 0.f) +
              fmaxf(g4.x * sv.x + sv.y, 0.f) + fmaxf(g5.x * sv.x + sv.y, 0.f) +
              fmaxf(g6.x * sv.x + sv.y, 0.f) + fmaxf(g7.x * sv.x + sv.y, 0.f);
        s1 += fmaxf(g0.y * sv.z + sv.w, 0.f) + fmaxf(g1.y * sv.z + sv.w, 0.f) +
              fmaxf(g2.y * sv.z + sv.w, 0.f) + fmaxf(g3.y * sv.z + sv.w, 0.f) +
              fmaxf(g4.y * sv.z + sv.w, 0.f) + fmaxf(g5.y * sv.z + sv.w, 0.f) +
              fmaxf(g6.y * sv.z + sv.w, 0.f) + fmaxf(g7.y * sv.z + sv.w, 0.f);
        if (aggOut) *(float2*)&aggOut[rg * 128 + 2 * l] = make_float2(s0, s1);
      }
      Xl[(2 * l) * 69 + row] = s0;
      Xl[(2 * l + 1) * 69 + row] = s1;
    }
  }
  __syncthreads();
  // ---- compute: acc over 16 wave-owned outs; W via scalar loads ----
  const float* Wp = W + (size_t)wv * 16 * 128;
  float acc[16];
#pragma unroll
  for (int o = 0; o < 16; o++) acc[o] = 0.f;
  for (int c0 = 0; c0 < 128; c0 += 4) {
    float x0 = Xl[(c0 + 0) * 69 + l];
    float x1 = Xl[(c0 + 1) * 69 + l];
    float x2 = Xl[(c0 + 2) * 69 + l];
    float x3 = Xl[(c0 + 3) * 69 + l];
#pragma unroll
    for (int o = 0; o < 16; o++) {
      const float* wr = Wp + o * 128 + c0;
      acc[o] = fmaf(wr[0], x0, fmaf(wr[1], x1, fmaf(wr[2], x2, fmaf(wr[3], x3, acc[o]))));
    }
  }
  // ---- epilogue ----
  int ow = wv * 16;
  size_t row = (size_t)(row0 + l);
#pragma unroll
  for (int g = 0; g < 4; g++) {
    float4 bv = *(const float4*)&bias[ow + g * 4];
    float4 v;
    v.x = acc[g * 4 + 0] * alpha + bv.x;
    v.y = acc[g * 4 + 1] * alpha + bv.y;
    v.z = acc[g * 4 + 2] * alpha + bv.z;
    v.w = acc[g * 4 + 3] * alpha + bv.w;
    if (addShortcut) {
      float4 sc = *(const float4*)&Xin[row * 128 + ow + g * 4];
      v.x += sc.x; v.y += sc.y; v.z += sc.z; v.w += sc.w;
    }
    *(float4*)&Y[row * 128 + ow + g * 4] = v;
    acc[g * 4 + 0] = v.x; acc[g * 4 + 1] = v.y; acc[g * 4 + 2] = v.z; acc[g * 4 + 3] = v.w;
  }
  if (partOut) {
#pragma unroll
    for (int o = 0; o < 16; o++) {
      float s = acc[o], q = acc[o] * acc[o];
#pragma unroll
      for (int off = 32; off; off >>= 1) { s += __shfl_xor(s, off); q += __shfl_xor(q, off); }
      if (l == 0) partOut[(size_t)(ow + o) * PSTR + blockIdx.x] = make_float2(s, q);
    }
  }
}

// ---------------- maxk (256 blocks) + transposed stats ----------------
__global__ __launch_bounds__(256) void maxk_kernel(const float* __restrict__ x,
                                                   const float2* __restrict__ ssIn,
                                                   float* __restrict__ outp, int ppb,
                                                   float2* __restrict__ partOut) {
  int wid = threadIdx.x >> 6, lane = threadIdx.x & 63;
  float2 sA = ssIn[2 * lane], sB = ssIn[2 * lane + 1];
  float ps0 = 0, pq0 = 0, ps1 = 0, pq1 = 0;
  for (int p = 0; p < ppb / 4; p++) {
    int pn = blockIdx.x * ppb + p * 4 + wid;
    const float* px = x + (size_t)pn * 8 * 128 + 2 * lane;
    float m0 = 0.f, m1 = 0.f;
#pragma unroll
    for (int k = 0; k < 8; k++) {
      float2 v = *(const float2*)(px + (size_t)k * 128);
      m0 = fmaxf(m0, v.x * sA.x + sA.y);
      m1 = fmaxf(m1, v.y * sB.x + sB.y);
    }
    *(float2*)&outp[(size_t)pn * 128 + 2 * lane] = make_float2(m0, m1);
    ps0 += m0; pq0 += m0 * m0; ps1 += m1; pq1 += m1 * m1;
  }
  __shared__ float4 red[4][64];
  red[wid][lane] = make_float4(ps0, pq0, ps1, pq1);
  __syncthreads();
  if (threadIdx.x < 64) {
    int t = threadIdx.x;
    float4 a = red[0][t], b2 = red[1][t], c2 = red[2][t], d2 = red[3][t];
    partOut[(size_t)(2 * t) * PSTR + blockIdx.x] =
        make_float2(a.x + b2.x + c2.x + d2.x, a.y + b2.y + c2.y + d2.y);
    partOut[(size_t)(2 * t + 1) * PSTR + blockIdx.x] =
        make_float2(a.z + b2.z + c2.z + d2.z, a.w + b2.w + c2.w + d2.w);
  }
}

// ---------------- gathermean (256 blocks) + transposed stats ----------------
__global__ __launch_bounds__(256) void gathermean_kernel(const float* __restrict__ pts,
                                                         const int* __restrict__ idx,
                                                         float* __restrict__ outp,
                                                         int Nin, int Nout, int rpb,
                                                         float2* __restrict__ partOut) {
  int wid = threadIdx.x >> 6, lane = threadIdx.x & 63;
  float ps0 = 0, pq0 = 0, ps1 = 0, pq1 = 0;
  for (int p = 0; p < rpb / 4; p++) {
    int r = blockIdx.x * rpb + p * 4 + wid;
    int bbase = (r / Nout) * Nin;
    const int4* ir = (const int4*)(idx + (size_t)r * 8);
    int4 j0 = ir[0], j1 = ir[1];
    int js[8] = {j0.x, j0.y, j0.z, j0.w, j1.x, j1.y, j1.z, j1.w};
    float sx = 0.f, sy = 0.f;
#pragma unroll
    for (int k = 0; k < 8; k++) {
      float2 v = *(const float2*)&pts[(size_t)(bbase + js[k]) * 128 + 2 * lane];
      sx += v.x; sy += v.y;
    }
    sx *= 0.125f; sy *= 0.125f;
    *(float2*)&outp[(size_t)r * 128 + 2 * lane] = make_float2(sx, sy);
    ps0 += sx; pq0 += sx * sx; ps1 += sy; pq1 += sy * sy;
  }
  __shared__ float4 red[4][64];
  red[wid][lane] = make_float4(ps0, pq0, ps1, pq1);
  __syncthreads();
  if (threadIdx.x < 64) {
    int t = threadIdx.x;
    float4 a = red[0][t], b2 = red[1][t], c2 = red[2][t], d2 = red[3][t];
    partOut[(size_t)(2 * t) * PSTR + blockIdx.x] =
        make_float2(a.x + b2.x + c2.x + d2.x, a.y + b2.y + c2.y + d2.y);
    partOut[(size_t)(2 * t + 1) * PSTR + blockIdx.x] =
        make_float2(a.z + b2.z + c2.z + d2.z, a.w + b2.w + c2.w + d2.w);
  }
}

// ---------------- newxyz ----------------
__global__ __launch_bounds__(256) void newxyz_kernel(
    const float* __restrict__ p, const float* __restrict__ agg,
    const float* __restrict__ Wc, const float* __restrict__ bc,
    const float* __restrict__ Wn, const float* __restrict__ bn_,
    const float* __restrict__ xyzc, float* __restrict__ outp, int N) {
  __shared__ float wc[6][128], wn[6][128];
  for (int i = threadIdx.x; i < 768; i += 256) { wc[i >> 7][i & 127] = Wc[i]; wn[i >> 7][i & 127] = Wn[i]; }
  __syncthreads();
  int pr = blockIdx.x * 4 + (threadIdx.x >> 6);
  int lane = threadIdx.x & 63;
  int b = pr / N, n = pr % N;
  float2 pv = *(const float2*)&p[(size_t)pr * 128 + 2 * lane];
  float2 av = *(const float2*)&agg[(size_t)pr * 128 + 2 * lane];
  float2 gv = make_float2(av.x - pv.x, av.y - pv.y);
  float a[6];
#pragma unroll
  for (int j = 0; j < 6; j++)
    a[j] = wc[j][2 * lane] * pv.x + wc[j][2 * lane + 1] * pv.y +
           wn[j][2 * lane] * gv.x + wn[j][2 * lane + 1] * gv.y;
#pragma unroll
  for (int j = 0; j < 6; j++)
#pragma unroll
    for (int off = 32; off; off >>= 1) a[j] += __shfl_xor(a[j], off);
  if (lane == 0) {
#pragma unroll
    for (int j = 0; j < 6; j++) {
      int d = j >> 1, u = j & 1;
      float v = (a[j] + bc[j] + 8.f * bn_[j]) * (1.f / 9.f);
      outp[((size_t)b * 3 + d) * (2 * N) + (size_t)u * N + n] = v + xyzc[((size_t)b * 3 + d) * N + n];
    }
  }
}

extern "C" void kernel_launch(void* const* d_in, const int* in_sizes, int n_in,
                              void* d_out, int out_size, void* d_ws, size_t ws_size,
                              hipStream_t stream) {
  const float* xyz    = (const float*)d_in[0];
  const float* fn_W0  = (const float*)d_in[1];
  const float* fn_b0  = (const float*)d_in[2];
  const float* fn_W   = (const float*)d_in[3];
  const float* fn_b   = (const float*)d_in[4];
  const float* fn_bng = (const float*)d_in[5];
  const float* fn_bnb = (const float*)d_in[6];
  const float* rb_bng = (const float*)d_in[7];
  const float* rb_bnb = (const float*)d_in[8];
  const float* rb_W   = (const float*)d_in[9];
  const float* rb_b   = (const float*)d_in[10];
  const float* rb_cW  = (const float*)d_in[11];
  const float* rb_cb  = (const float*)d_in[12];
  const float* rb_nW  = (const float*)d_in[13];
  const float* rb_nb  = (const float*)d_in[14];
  float* out = (float*)d_out;

  const int N1 = 2048, N2 = 4096;
  const int RT0 = NB * N1 * 8;   // 131072
  const int RT1 = NB * N1;       // 16384
  const int RT2 = NB * N2;       // 32768
  char* ws = (char*)d_ws;
  float* A = (float*)ws;                          // 64 MiB
  float* B = (float*)(ws + ((size_t)64 << 20));   // 64 MiB
  char* tail = ws + ((size_t)128 << 20);
  int* idx1 = (int*)tail;    tail += (size_t)RT1 * 8 * 4;
  int* idxI = (int*)tail;    tail += (size_t)RT2 * 8 * 4;
  int* idx2 = (int*)tail;    tail += (size_t)RT2 * 8 * 4;
  float* nx1 = (float*)tail; tail += (size_t)NB * 3 * N2 * 4;
  float2* partials = (float2*)tail; tail += (size_t)128 * PSTR * sizeof(float2);
  float2* ssb = (float2*)tail; tail += 128 * sizeof(float2);
  float4* ref4a = (float4*)tail; tail += (size_t)RT1 * sizeof(float4);
  float4* ref4b = (float4*)tail; tail += (size_t)RT2 * sizeof(float4);

  float* X0 = A;
  float* X1 = B;
  const size_t M8 = (size_t)(8 << 20) / 4;
  float* pts1a = B;            float* pts1b = B + M8;
  float* p1 = B + 2 * M8;      float* agg1 = B + 3 * M8;
  const size_t M16 = (size_t)(16 << 20) / 4;
  float* pts2a = A;            float* pts2b = A + M16;
  float* p2 = A + 2 * M16;     float* agg2 = A + 3 * M16;

  // ---------- featurenet ----------
  pack_kernel<<<RT1 / 256, 256, 0, stream>>>(xyz, ref4a, N1);
  knn_kernel<true><<<dim3(N1 / 4, NB), 256, 0, stream>>>(ref4a, xyz, N1, N1, idx1);
  conv0stats_kernel<<<256, 256, 0, stream>>>(xyz, idx1, fn_W0, fn_b0, X0, N1, RT0 / 256, partials);
  finalize_kernel<<<128, 64, 0, stream>>>(partials, 256, 1.f / (float)RT0, fn_bng, fn_bnb, ssb);
  gemmv_kernel<false><<<RT0 / 64, 512, 0, stream>>>(X0, ssb, nullptr, 0, 0.f, nullptr, nullptr,
      nullptr, fn_W, fn_b, X1, partials, nullptr, nullptr, 1, 1.f, 0);
  finalize_kernel<<<128, 64, 0, stream>>>(partials, RT0 / 64, 1.f / (float)RT0,
                                          fn_bng + 128, fn_bnb + 128, ssb);
  gemmv_kernel<false><<<RT0 / 64, 512, 0, stream>>>(X1, ssb, nullptr, 0, 0.f, nullptr, nullptr,
      nullptr, fn_W + 16384, fn_b + 128, X0, partials, nullptr, nullptr, 1, 1.f, 0);
  finalize_kernel<<<128, 64, 0, stream>>>(partials, RT0 / 64, 1.f / (float)RT0,
                                          fn_bng + 256, fn_bnb + 256, ssb);
  maxk_kernel<<<256, 256, 0, stream>>>(X0, ssb, pts1a, RT1 / 256, partials);

  // ---------- stage 0 (N=2048): BN reduce fused into gemm prologue ----------
  float* cur = pts1a;
  float* alt = pts1b;
  for (int i = 0; i < 12; i++) {
    bool last = (i == 11);
    gemmv_kernel<true><<<RT1 / 64, 512, 0, stream>>>(cur, nullptr, partials, 256,
        1.f / (float)RT1, rb_bng + i * 128, rb_bnb + i * 128,
        idx1, rb_W + (size_t)i * 16384, rb_b + i * 128, alt,
        last ? nullptr : partials, last ? p1 : nullptr, last ? agg1 : nullptr,
        N1, 1.f / 9.f, 1);
    float* t = cur; cur = alt; alt = t;
  }
  newxyz_kernel<<<RT1 / 4, 256, 0, stream>>>(p1, agg1, rb_cW, rb_cb, rb_nW, rb_nb, xyz, nx1, N1);

  // ---------- interp to 4096 ----------
  pack_kernel<<<RT2 / 256, 256, 0, stream>>>(nx1, ref4b, N2);
  knn_kernel<false><<<dim3(N2 / 4, NB), 256, 0, stream>>>(ref4a, nx1, N1, N2, idxI);
  gathermean_kernel<<<256, 256, 0, stream>>>(cur, idxI, pts2a, N1, N2, RT2 / 256, partials);
  knn_kernel<true><<<dim3(N2 / 4, NB), 256, 0, stream>>>(ref4b, nx1, N2, N2, idx2);

  // ---------- stage 1 (N=4096): BN reduce fused into gemm prologue ----------
  cur = pts2a; alt = pts2b;
  for (int i = 0; i < 12; i++) {
    bool last = (i == 11);
    gemmv_kernel<true><<<RT2 / 64, 512, 0, stream>>>(cur, nullptr, partials, (i == 0) ? 256 : RT2 / 64,
        1.f / (float)RT2, rb_bng + (12 + i) * 128, rb_bnb + (12 + i) * 128,
        idx2, rb_W + (size_t)(12 + i) * 16384, rb_b + (12 + i) * 128, alt,
        last ? nullptr : partials, last ? p2 : nullptr, last ? agg2 : nullptr,
        N2, 1.f / 9.f, 1);
    float* t = cur; cur = alt; alt = t;
  }
  newxyz_kernel<<<RT2 / 4, 256, 0, stream>>>(p2, agg2, rb_cW + 768, rb_cb + 6,
                                             rb_nW + 768, rb_nb + 6, nx1, out, N2);
}

// Round 16
// 1536.481 us; speedup vs baseline: 1.4763x; 1.4763x over previous
//
#include <hip/hip_runtime.h>

#define NB 8
#define KNBR 8
#define SCAP 256
#define PSTR 4096   // partials row stride (max producer grid)

// ---------------- pack: ref4[r] = (x,y,z,|p|^2) ----------------
__global__ void pack_kernel(const float* __restrict__ xyz, float4* __restrict__ outp, int N) {
  int r = blockIdx.x * 256 + threadIdx.x;
  int b = r / N, n = r - b * N;
  const float* xb = xyz + (size_t)b * 3 * N;
  float x = xb[n], y = xb[N + n], z = xb[2 * N + n];
  outp[r] = make_float4(x, y, z, x * x + y * y + z * z);
}

// ---------------- KNN: wave-per-query, global packed refs, tau-filter + compact (exact) ----------
template<bool EXCL>
__global__ __launch_bounds__(256) void knn_kernel(const float4* __restrict__ ref4,
                                                  const float* __restrict__ qry,
                                                  int Nr, int Nq, int* __restrict__ idx_out) {
  __shared__ float2 surv[4][SCAP];      // 8 KB
  int b = blockIdx.y;
  int wid = threadIdx.x >> 6, lane = threadIdx.x & 63;
  int qi = blockIdx.x * 4 + wid;
  const float4* rb = ref4 + (size_t)b * Nr;
  const float* qb = qry + (size_t)b * 3 * Nq;
  float m2qx = -2.f * qb[qi], m2qy = -2.f * qb[Nq + qi], m2qz = -2.f * qb[2 * Nq + qi];
  float bd[8]; int bi[8];
#pragma unroll
  for (int t = 0; t < 8; t++) { bd[t] = 3.4e38f; bi[t] = 0; }
  float4 rr[8];
  // ---- phase 1: exact top-8 of first 512 ----
#pragma unroll
  for (int u = 0; u < 8; u++) rr[u] = rb[u * 64 + lane];
#pragma unroll
  for (int u = 0; u < 8; u++) {
    float d = fmaf(m2qx, rr[u].x, fmaf(m2qy, rr[u].y, fmaf(m2qz, rr[u].z, rr[u].w)));
    int j = u * 64 + lane;
    if (EXCL) d = (j == qi) ? 3.4e38f : d;
    if (d < bd[7]) {
      bd[7] = d; bi[7] = j;
#pragma unroll
      for (int t = 7; t > 0; t--)
        if (bd[t] < bd[t - 1]) {
          float td = bd[t]; bd[t] = bd[t - 1]; bd[t - 1] = td;
          int ti = bi[t]; bi[t] = bi[t - 1]; bi[t - 1] = ti;
        }
    }
  }
  {  // merge across lanes; replicate merged top-8 into every lane
    float nd[8]; int ni[8];
#pragma unroll
    for (int r = 0; r < 8; r++) {
      float d = bd[0]; int ix = bi[0];
#pragma unroll
      for (int off = 32; off; off >>= 1) {
        float d2 = __shfl_xor(d, off); int i2 = __shfl_xor(ix, off);
        if (d2 < d || (d2 == d && i2 < ix)) { d = d2; ix = i2; }
      }
      if (bd[0] == d && bi[0] == ix) {
#pragma unroll
        for (int t = 0; t < 7; t++) { bd[t] = bd[t + 1]; bi[t] = bi[t + 1]; }
        bd[7] = 3.4e38f;
      }
      nd[r] = d; ni[r] = ix;
    }
#pragma unroll
    for (int t = 0; t < 8; t++) { bd[t] = nd[t]; bi[t] = ni[t]; }
  }
  float tau = bd[7];
  // ---- phase 2: filter + ballot-compact ----
  int scnt = 0;
  for (int base = 512; base < Nr; base += 512) {
#pragma unroll
    for (int u = 0; u < 8; u++) rr[u] = rb[base + u * 64 + lane];
#pragma unroll
    for (int u = 0; u < 8; u++) {
      float d = fmaf(m2qx, rr[u].x, fmaf(m2qy, rr[u].y, fmaf(m2qz, rr[u].z, rr[u].w)));
      int gj = base + u * 64 + lane;
      bool pass = d < tau;
      if (EXCL) pass = pass && (gj != qi);
      if (__any(pass)) {
        unsigned long long mask = __ballot(pass);
        int below = (int)__builtin_amdgcn_mbcnt_hi(
            (unsigned)(mask >> 32), __builtin_amdgcn_mbcnt_lo((unsigned)mask, 0u));
        if (pass) {
          int pos = scnt + below;
          if (pos < SCAP) surv[wid][pos] = make_float2(d, __int_as_float(gj));
        }
        scnt += (int)__popcll(mask);
      }
    }
  }
  // ---- phase 3: insert survivors, final exact wave merge ----
  int nsurv = min(scnt, SCAP);
  for (int s2 = lane; s2 < nsurv; s2 += 64) {
    float2 v = surv[wid][s2];
    float d = v.x; int gj = __float_as_int(v.y);
    if (d < bd[7]) {
      bd[7] = d; bi[7] = gj;
#pragma unroll
      for (int t = 7; t > 0; t--)
        if (bd[t] < bd[t - 1]) {
          float td = bd[t]; bd[t] = bd[t - 1]; bd[t - 1] = td;
          int ti = bi[t]; bi[t] = bi[t - 1]; bi[t - 1] = ti;
        }
    }
  }
  int myout = 0;
#pragma unroll
  for (int r = 0; r < 8; r++) {
    float d = bd[0]; int ix = bi[0];
#pragma unroll
    for (int off = 32; off; off >>= 1) {
      float d2 = __shfl_xor(d, off); int i2 = __shfl_xor(ix, off);
      if (d2 < d || (d2 == d && i2 < ix)) { d = d2; ix = i2; }
    }
    if (bd[0] == d && bi[0] == ix) {
#pragma unroll
      for (int t = 0; t < 7; t++) { bd[t] = bd[t + 1]; bi[t] = bi[t + 1]; }
      bd[7] = 3.4e38f;
    }
    if (lane == r) myout = ix;
  }
  if (lane < 8) idx_out[((size_t)b * Nq + qi) * 8 + lane] = myout;
}

// ---------------- conv0 + fused stats (256 blocks) ----------------
__global__ __launch_bounds__(256) void conv0stats_kernel(const float* __restrict__ xyz,
                                                         const int* __restrict__ idx,
                                                         const float* __restrict__ W0,
                                                         const float* __restrict__ b0,
                                                         float* __restrict__ outp, int N, int rpb,
                                                         float2* __restrict__ partOut) {
  int wid = threadIdx.x >> 6, lane = threadIdx.x & 63;
  int o = 2 * lane;
  float w00 = W0[o * 3], w01 = W0[o * 3 + 1], w02 = W0[o * 3 + 2], bb0 = b0[o];
  float w10 = W0[o * 3 + 3], w11 = W0[o * 3 + 4], w12 = W0[o * 3 + 5], bb1 = b0[o + 1];
  float ps0 = 0, pq0 = 0, ps1 = 0, pq1 = 0;
  for (int p = 0; p < rpb / 4; p++) {
    int r = blockIdx.x * rpb + p * 4 + wid;
    int k = r & 7, pn = r >> 3;
    int n = pn & (N - 1), b = pn / N;
    const float* xb = xyz + (size_t)b * 3 * N;
    int j = idx[(size_t)pn * 8 + k];
    float dx = xb[j] - xb[n], dy = xb[N + j] - xb[N + n], dz = xb[2 * N + j] - xb[2 * N + n];
    float v0 = fmaf(w00, dx, fmaf(w01, dy, fmaf(w02, dz, bb0)));
    float v1 = fmaf(w10, dx, fmaf(w11, dy, fmaf(w12, dz, bb1)));
    *(float2*)&outp[(size_t)r * 128 + o] = make_float2(v0, v1);
    ps0 += v0; pq0 += v0 * v0; ps1 += v1; pq1 += v1 * v1;
  }
  __shared__ float4 red[4][64];
  red[wid][lane] = make_float4(ps0, pq0, ps1, pq1);
  __syncthreads();
  if (threadIdx.x < 64) {
    int t = threadIdx.x;
    float4 a = red[0][t], b2 = red[1][t], c2 = red[2][t], d2 = red[3][t];
    partOut[(size_t)(2 * t) * PSTR + blockIdx.x] =
        make_float2(a.x + b2.x + c2.x + d2.x, a.y + b2.y + c2.y + d2.y);
    partOut[(size_t)(2 * t + 1) * PSTR + blockIdx.x] =
        make_float2(a.z + b2.z + c2.z + d2.z, a.w + b2.w + c2.w + d2.w);
  }
}

// ---------------- finalize: transposed partials -> ss (parallel, coalesced) ----------------
__global__ void finalize_kernel(const float2* __restrict__ partials, int nblk, float cntInv,
                                const float* __restrict__ gamma, const float* __restrict__ beta,
                                float2* __restrict__ ss) {
  int c = blockIdx.x;
  const float2* p = partials + (size_t)c * PSTR;
  float s = 0, q = 0;
  for (int i = threadIdx.x; i < nblk; i += 64) { float2 v = p[i]; s += v.x; q += v.y; }
#pragma unroll
  for (int off = 32; off; off >>= 1) { s += __shfl_xor(s, off); q += __shfl_xor(q, off); }
  if (threadIdx.x == 0) {
    float mean = s * cntInv;
    float var = q * cntInv - mean * mean;
    float sc = gamma[c] * rsqrtf(var + 1e-5f);
    ss[c] = make_float2(sc, beta[c] - mean * sc);
  }
}

// ---------------- gemmv: wave-uniform W (scalar loads), lane=row, full-K LDS X ----------------
// Block: 512 thr (8 waves), 64 rows x 128 outs. Wave wv owns outs [wv*16, wv*16+16), lane = row.
// W addresses wave-uniform via readfirstlane -> s_load path (no LDS, no VGPR for W).
// Xl[128ch][69rows]: compute reads consecutive-lane b32 (conflict-free); gathers staged ONCE.
template<bool GATHER>
__global__ __launch_bounds__(512) void gemmv_kernel(
    const float* __restrict__ Xin, const float2* __restrict__ ss,
    const int* __restrict__ idx, const float* __restrict__ W,
    const float* __restrict__ bias, float* __restrict__ Y,
    float2* __restrict__ partOut, float* __restrict__ pOut, float* __restrict__ aggOut,
    int N, float alpha, int addShortcut) {
  __shared__ float Xl[128 * 69];   // 34.5 KB
  int tid = threadIdx.x;
  int l = tid & 63;
  int wv = __builtin_amdgcn_readfirstlane(tid >> 6);
  int row0;
  if (GATHER) row0 = (blockIdx.x & 7) * N + (blockIdx.x >> 3) * 64;  // XCD-batch swizzle
  else        row0 = blockIdx.x * 64;
  // ---- stage: wave wv stages rows wv*8..wv*8+7; lane covers channels 2l, 2l+1 ----
  {
    float4 sv = *(const float4*)&ss[2 * l];   // (scale0,shift0,scale1,shift1)
    for (int r8 = 0; r8 < 8; ++r8) {
      int row = wv * 8 + r8;
      size_t rg = (size_t)(row0 + row);
      float2 v = *(const float2*)&Xin[rg * 128 + 2 * l];
      float s0 = fmaxf(v.x * sv.x + sv.y, 0.f);
      float s1 = fmaxf(v.y * sv.z + sv.w, 0.f);
      if (GATHER) {
        if (pOut) *(float2*)&pOut[rg * 128 + 2 * l] = make_float2(s0, s1);
        int bN = (int)rg & ~(N - 1);
        const int* ir = idx + rg * 8;
        int4 j0 = *(const int4*)ir;
        int4 j1 = *(const int4*)(ir + 4);
        float2 g0 = *(const float2*)&Xin[(size_t)(bN + j0.x) * 128 + 2 * l];
        float2 g1 = *(const float2*)&Xin[(size_t)(bN + j0.y) * 128 + 2 * l];
        float2 g2 = *(const float2*)&Xin[(size_t)(bN + j0.z) * 128 + 2 * l];
        float2 g3 = *(const float2*)&Xin[(size_t)(bN + j0.w) * 128 + 2 * l];
        float2 g4 = *(const float2*)&Xin[(size_t)(bN + j1.x) * 128 + 2 * l];
        float2 g5 = *(const float2*)&Xin[(size_t)(bN + j1.y) * 128 + 2 * l];
        float2 g6 = *(const float2*)&Xin[(size_t)(bN + j1.z) * 128 + 2 * l];
        float2 g7 = *(const float2*)&Xin[(size_t)(bN + j1.w) * 128 + 2 * l];
        s0 += fmaxf(g0.x * sv.x + sv.y, 0.f) + fmaxf(g1.x * sv.x + sv.y, 0.f) +
              fmaxf(g2.x * sv.x + sv.y, 0.f) + fmaxf(g3.x * sv.x + sv.y, 0.f) +
              fmaxf(g4.x * sv.x + sv.y, 0.f) + fmaxf(g5.x * sv.x + sv.y, 0.f) +
              fmaxf(g6.x * sv.x + sv.y, 0.f) + fmaxf(g7.x * sv.x + sv.y, 0.f);
        s1 += fmaxf(g0.y * sv.z + sv.w, 0.f) + fmaxf(g1.y * sv.z + sv.w, 0.f) +
              fmaxf(g2.y * sv.z + sv.w, 0.f) + fmaxf(g3.y * sv.z + sv.w, 0.f) +
              fmaxf(g4.y * sv.z + sv.w, 0.f) + fmaxf(g5.y * sv.z + sv.w, 0.f) +
              fmaxf(g6.y * sv.z + sv.w, 0.f) + fmaxf(g7.y * sv.z + sv.w, 0.f);
        if (aggOut) *(float2*)&aggOut[rg * 128 + 2 * l] = make_float2(s0, s1);
      }
      Xl[(2 * l) * 69 + row] = s0;
      Xl[(2 * l + 1) * 69 + row] = s1;
    }
  }
  __syncthreads();
  // ---- compute: acc over 16 wave-owned outs; W via scalar loads ----
  const float* Wp = W + (size_t)wv * 16 * 128;
  float acc[16];
#pragma unroll
  for (int o = 0; o < 16; o++) acc[o] = 0.f;
  for (int c0 = 0; c0 < 128; c0 += 4) {
    float x0 = Xl[(c0 + 0) * 69 + l];
    float x1 = Xl[(c0 + 1) * 69 + l];
    float x2 = Xl[(c0 + 2) * 69 + l];
    float x3 = Xl[(c0 + 3) * 69 + l];
#pragma unroll
    for (int o = 0; o < 16; o++) {
      const float* wr = Wp + o * 128 + c0;
      acc[o] = fmaf(wr[0], x0, fmaf(wr[1], x1, fmaf(wr[2], x2, fmaf(wr[3], x3, acc[o]))));
    }
  }
  // ---- epilogue ----
  int ow = wv * 16;
  size_t row = (size_t)(row0 + l);
#pragma unroll
  for (int g = 0; g < 4; g++) {
    float4 bv = *(const float4*)&bias[ow + g * 4];
    float4 v;
    v.x = acc[g * 4 + 0] * alpha + bv.x;
    v.y = acc[g * 4 + 1] * alpha + bv.y;
    v.z = acc[g * 4 + 2] * alpha + bv.z;
    v.w = acc[g * 4 + 3] * alpha + bv.w;
    if (addShortcut) {
      float4 sc = *(const float4*)&Xin[row * 128 + ow + g * 4];
      v.x += sc.x; v.y += sc.y; v.z += sc.z; v.w += sc.w;
    }
    *(float4*)&Y[row * 128 + ow + g * 4] = v;
    acc[g * 4 + 0] = v.x; acc[g * 4 + 1] = v.y; acc[g * 4 + 2] = v.z; acc[g * 4 + 3] = v.w;
  }
  if (partOut) {
#pragma unroll
    for (int o = 0; o < 16; o++) {
      float s = acc[o], q = acc[o] * acc[o];
#pragma unroll
      for (int off = 32; off; off >>= 1) { s += __shfl_xor(s, off); q += __shfl_xor(q, off); }
      if (l == 0) partOut[(size_t)(ow + o) * PSTR + blockIdx.x] = make_float2(s, q);
    }
  }
}

// ---------------- maxk (256 blocks) + transposed stats ----------------
__global__ __launch_bounds__(256) void maxk_kernel(const float* __restrict__ x,
                                                   const float2* __restrict__ ssIn,
                                                   float* __restrict__ outp, int ppb,
                                                   float2* __restrict__ partOut) {
  int wid = threadIdx.x >> 6, lane = threadIdx.x & 63;
  float2 sA = ssIn[2 * lane], sB = ssIn[2 * lane + 1];
  float ps0 = 0, pq0 = 0, ps1 = 0, pq1 = 0;
  for (int p = 0; p < ppb / 4; p++) {
    int pn = blockIdx.x * ppb + p * 4 + wid;
    const float* px = x + (size_t)pn * 8 * 128 + 2 * lane;
    float m0 = 0.f, m1 = 0.f;
#pragma unroll
    for (int k = 0; k < 8; k++) {
      float2 v = *(const float2*)(px + (size_t)k * 128);
      m0 = fmaxf(m0, v.x * sA.x + sA.y);
      m1 = fmaxf(m1, v.y * sB.x + sB.y);
    }
    *(float2*)&outp[(size_t)pn * 128 + 2 * lane] = make_float2(m0, m1);
    ps0 += m0; pq0 += m0 * m0; ps1 += m1; pq1 += m1 * m1;
  }
  __shared__ float4 red[4][64];
  red[wid][lane] = make_float4(ps0, pq0, ps1, pq1);
  __syncthreads();
  if (threadIdx.x < 64) {
    int t = threadIdx.x;
    float4 a = red[0][t], b2 = red[1][t], c2 = red[2][t], d2 = red[3][t];
    partOut[(size_t)(2 * t) * PSTR + blockIdx.x] =
        make_float2(a.x + b2.x + c2.x + d2.x, a.y + b2.y + c2.y + d2.y);
    partOut[(size_t)(2 * t + 1) * PSTR + blockIdx.x] =
        make_float2(a.z + b2.z + c2.z + d2.z, a.w + b2.w + c2.w + d2.w);
  }
}

// ---------------- gathermean (256 blocks) + transposed stats ----------------
__global__ __launch_bounds__(256) void gathermean_kernel(const float* __restrict__ pts,
                                                         const int* __restrict__ idx,
                                                         float* __restrict__ outp,
                                                         int Nin, int Nout, int rpb,
                                                         float2* __restrict__ partOut) {
  int wid = threadIdx.x >> 6, lane = threadIdx.x & 63;
  float ps0 = 0, pq0 = 0, ps1 = 0, pq1 = 0;
  for (int p = 0; p < rpb / 4; p++) {
    int r = blockIdx.x * rpb + p * 4 + wid;
    int bbase = (r / Nout) * Nin;
    const int4* ir = (const int4*)(idx + (size_t)r * 8);
    int4 j0 = ir[0], j1 = ir[1];
    int js[8] = {j0.x, j0.y, j0.z, j0.w, j1.x, j1.y, j1.z, j1.w};
    float sx = 0.f, sy = 0.f;
#pragma unroll
    for (int k = 0; k < 8; k++) {
      float2 v = *(const float2*)&pts[(size_t)(bbase + js[k]) * 128 + 2 * lane];
      sx += v.x; sy += v.y;
    }
    sx *= 0.125f; sy *= 0.125f;
    *(float2*)&outp[(size_t)r * 128 + 2 * lane] = make_float2(sx, sy);
    ps0 += sx; pq0 += sx * sx; ps1 += sy; pq1 += sy * sy;
  }
  __shared__ float4 red[4][64];
  red[wid][lane] = make_float4(ps0, pq0, ps1, pq1);
  __syncthreads();
  if (threadIdx.x < 64) {
    int t = threadIdx.x;
    float4 a = red[0][t], b2 = red[1][t], c2 = red[2][t], d2 = red[3][t];
    partOut[(size_t)(2 * t) * PSTR + blockIdx.x] =
        make_float2(a.x + b2.x + c2.x + d2.x, a.y + b2.y + c2.y + d2.y);
    partOut[(size_t)(2 * t + 1) * PSTR + blockIdx.x] =
        make_float2(a.z + b2.z + c2.z + d2.z, a.w + b2.w + c2.w + d2.w);
  }
}

// ---------------- newxyz ----------------
__global__ __launch_bounds__(256) void newxyz_kernel(
    const float* __restrict__ p, const float* __restrict__ agg,
    const float* __restrict__ Wc, const float* __restrict__ bc,
    const float* __restrict__ Wn, const float* __restrict__ bn_,
    const float* __restrict__ xyzc, float* __restrict__ outp, int N) {
  __shared__ float wc[6][128], wn[6][128];
  for (int i = threadIdx.x; i < 768; i += 256) { wc[i >> 7][i & 127] = Wc[i]; wn[i >> 7][i & 127] = Wn[i]; }
  __syncthreads();
  int pr = blockIdx.x * 4 + (threadIdx.x >> 6);
  int lane = threadIdx.x & 63;
  int b = pr / N, n = pr % N;
  float2 pv = *(const float2*)&p[(size_t)pr * 128 + 2 * lane];
  float2 av = *(const float2*)&agg[(size_t)pr * 128 + 2 * lane];
  float2 gv = make_float2(av.x - pv.x, av.y - pv.y);
  float a[6];
#pragma unroll
  for (int j = 0; j < 6; j++)
    a[j] = wc[j][2 * lane] * pv.x + wc[j][2 * lane + 1] * pv.y +
           wn[j][2 * lane] * gv.x + wn[j][2 * lane + 1] * gv.y;
#pragma unroll
  for (int j = 0; j < 6; j++)
#pragma unroll
    for (int off = 32; off; off >>= 1) a[j] += __shfl_xor(a[j], off);
  if (lane == 0) {
#pragma unroll
    for (int j = 0; j < 6; j++) {
      int d = j >> 1, u = j & 1;
      float v = (a[j] + bc[j] + 8.f * bn_[j]) * (1.f / 9.f);
      outp[((size_t)b * 3 + d) * (2 * N) + (size_t)u * N + n] = v + xyzc[((size_t)b * 3 + d) * N + n];
    }
  }
}

extern "C" void kernel_launch(void* const* d_in, const int* in_sizes, int n_in,
                              void* d_out, int out_size, void* d_ws, size_t ws_size,
                              hipStream_t stream) {
  const float* xyz    = (const float*)d_in[0];
  const float* fn_W0  = (const float*)d_in[1];
  const float* fn_b0  = (const float*)d_in[2];
  const float* fn_W   = (const float*)d_in[3];
  const float* fn_b   = (const float*)d_in[4];
  const float* fn_bng = (const float*)d_in[5];
  const float* fn_bnb = (const float*)d_in[6];
  const float* rb_bng = (const float*)d_in[7];
  const float* rb_bnb = (const float*)d_in[8];
  const float* rb_W   = (const float*)d_in[9];
  const float* rb_b   = (const float*)d_in[10];
  const float* rb_cW  = (const float*)d_in[11];
  const float* rb_cb  = (const float*)d_in[12];
  const float* rb_nW  = (const float*)d_in[13];
  const float* rb_nb  = (const float*)d_in[14];
  float* out = (float*)d_out;

  const int N1 = 2048, N2 = 4096;
  const int RT0 = NB * N1 * 8;   // 131072
  const int RT1 = NB * N1;       // 16384
  const int RT2 = NB * N2;       // 32768
  char* ws = (char*)d_ws;
  float* A = (float*)ws;                          // 64 MiB
  float* B = (float*)(ws + ((size_t)64 << 20));   // 64 MiB
  char* tail = ws + ((size_t)128 << 20);
  int* idx1 = (int*)tail;    tail += (size_t)RT1 * 8 * 4;
  int* idxI = (int*)tail;    tail += (size_t)RT2 * 8 * 4;
  int* idx2 = (int*)tail;    tail += (size_t)RT2 * 8 * 4;
  float* nx1 = (float*)tail; tail += (size_t)NB * 3 * N2 * 4;
  float2* partials = (float2*)tail; tail += (size_t)128 * PSTR * sizeof(float2);
  float2* ssb = (float2*)tail; tail += 128 * sizeof(float2);
  float4* ref4a = (float4*)tail; tail += (size_t)RT1 * sizeof(float4);
  float4* ref4b = (float4*)tail; tail += (size_t)RT2 * sizeof(float4);

  float* X0 = A;
  float* X1 = B;
  const size_t M8 = (size_t)(8 << 20) / 4;
  float* pts1a = B;            float* pts1b = B + M8;
  float* p1 = B + 2 * M8;      float* agg1 = B + 3 * M8;
  const size_t M16 = (size_t)(16 << 20) / 4;
  float* pts2a = A;            float* pts2b = A + M16;
  float* p2 = A + 2 * M16;     float* agg2 = A + 3 * M16;

  // ---------- featurenet ----------
  pack_kernel<<<RT1 / 256, 256, 0, stream>>>(xyz, ref4a, N1);
  knn_kernel<true><<<dim3(N1 / 4, NB), 256, 0, stream>>>(ref4a, xyz, N1, N1, idx1);
  conv0stats_kernel<<<256, 256, 0, stream>>>(xyz, idx1, fn_W0, fn_b0, X0, N1, RT0 / 256, partials);
  finalize_kernel<<<128, 64, 0, stream>>>(partials, 256, 1.f / (float)RT0, fn_bng, fn_bnb, ssb);
  gemmv_kernel<false><<<RT0 / 64, 512, 0, stream>>>(X0, ssb, nullptr, fn_W, fn_b, X1,
                                                    partials, nullptr, nullptr, 1, 1.f, 0);
  finalize_kernel<<<128, 64, 0, stream>>>(partials, RT0 / 64, 1.f / (float)RT0,
                                          fn_bng + 128, fn_bnb + 128, ssb);
  gemmv_kernel<false><<<RT0 / 64, 512, 0, stream>>>(X1, ssb, nullptr, fn_W + 16384, fn_b + 128, X0,
                                                    partials, nullptr, nullptr, 1, 1.f, 0);
  finalize_kernel<<<128, 64, 0, stream>>>(partials, RT0 / 64, 1.f / (float)RT0,
                                          fn_bng + 256, fn_bnb + 256, ssb);
  maxk_kernel<<<256, 256, 0, stream>>>(X0, ssb, pts1a, RT1 / 256, partials);

  // ---------- stage 0 (N=2048) ----------
  float* cur = pts1a;
  float* alt = pts1b;
  for (int i = 0; i < 12; i++) {
    bool last = (i == 11);
    finalize_kernel<<<128, 64, 0, stream>>>(partials, 256,
                                            1.f / (float)RT1, rb_bng + i * 128, rb_bnb + i * 128, ssb);
    gemmv_kernel<true><<<RT1 / 64, 512, 0, stream>>>(cur, ssb, idx1, rb_W + (size_t)i * 16384,
                                                     rb_b + i * 128, alt,
                                                     last ? nullptr : partials,
                                                     last ? p1 : nullptr, last ? agg1 : nullptr,
                                                     N1, 1.f / 9.f, 1);
    float* t = cur; cur = alt; alt = t;
  }
  newxyz_kernel<<<RT1 / 4, 256, 0, stream>>>(p1, agg1, rb_cW, rb_cb, rb_nW, rb_nb, xyz, nx1, N1);

  // ---------- interp to 4096 ----------
  pack_kernel<<<RT2 / 256, 256, 0, stream>>>(nx1, ref4b, N2);
  knn_kernel<false><<<dim3(N2 / 4, NB), 256, 0, stream>>>(ref4a, nx1, N1, N2, idxI);
  gathermean_kernel<<<256, 256, 0, stream>>>(cur, idxI, pts2a, N1, N2, RT2 / 256, partials);
  knn_kernel<true><<<dim3(N2 / 4, NB), 256, 0, stream>>>(ref4b, nx1, N2, N2, idx2);

  // ---------- stage 1 (N=4096) ----------
  cur = pts2a; alt = pts2b;
  for (int i = 0; i < 12; i++) {
    bool last = (i == 11);
    finalize_kernel<<<128, 64, 0, stream>>>(partials, (i == 0) ? 256 : RT2 / 64,
                                            1.f / (float)RT2, rb_bng + (12 + i) * 128,
                                            rb_bnb + (12 + i) * 128, ssb);
    gemmv_kernel<true><<<RT2 / 64, 512, 0, stream>>>(cur, ssb, idx2, rb_W + (size_t)(12 + i) * 16384,
                                                     rb_b + (12 + i) * 128, alt,
                                                     last ? nullptr : partials,
                                                     last ? p2 : nullptr, last ? agg2 : nullptr,
                                                     N2, 1.f / 9.f, 1);
    float* t = cur; cur = alt; alt = t;
  }
  newxyz_kernel<<<RT2 / 4, 256, 0, stream>>>(p2, agg2, rb_cW + 768, rb_cb + 6,
                                             rb_nW + 768, rb_nb + 6, nx1, out, N2);
}